// Round 17
// baseline (262.474 us; speedup 1.0000x reference)
//
#include <hip/hip_runtime.h>

#define B_ 32
#define N_ 512
#define C_ 1024
#define H_ 16
#define D_ 64
#define TC_ 3072
#define NQK_ 2048
#define M_ (B_*N_)

typedef unsigned int u32;
typedef unsigned short u16;
typedef __attribute__((ext_vector_type(8))) unsigned short ushort8;
typedef __attribute__((ext_vector_type(8))) short bf16x8;   // 8 bf16 (4 VGPRs)
typedef __attribute__((ext_vector_type(4))) float f32x4;

__device__ __forceinline__ float bfl(u32 u){ return __builtin_bit_cast(float, u << 16); }
__device__ __forceinline__ u16 f2bf(float f){
  u32 u = __builtin_bit_cast(u32, f);
  u32 r = (u + 0x7FFFu + ((u >> 16) & 1u)) >> 16;
  return (u16)r;
}

// ------------- fused prelude: LN (blocks 0..16383) + W-transpose (16384..18431) -------------
__global__ __launch_bounds__(256) void k_pre(const float* __restrict__ r,
                                             const float* __restrict__ g,
                                             const float* __restrict__ be,
                                             const float* __restrict__ W,
                                             u16* __restrict__ X,
                                             u16* __restrict__ WT) {
  __shared__ float tile[32][33];     // wcvt path (ln path uses first 8 floats)
  int bid = blockIdx.x, t = threadIdx.x;
  if (bid < M_) {
    float* red = &tile[0][0];
    int row = bid;
    float4 v = ((const float4*)(r + (size_t)row * C_))[t];
    float s = (v.x + v.y) + (v.z + v.w);
    #pragma unroll
    for (int o = 32; o; o >>= 1) s += __shfl_xor(s, o);
    if ((t & 63) == 0) red[t >> 6] = s;
    __syncthreads();
    float mean = (red[0] + red[1] + red[2] + red[3]) * (1.f / 1024.f);
    float d0 = v.x - mean, d1 = v.y - mean, d2 = v.z - mean, d3 = v.w - mean;
    float q = d0*d0 + d1*d1 + d2*d2 + d3*d3;
    #pragma unroll
    for (int o = 32; o; o >>= 1) q += __shfl_xor(q, o);
    if ((t & 63) == 0) red[4 + (t >> 6)] = q;
    __syncthreads();
    float var = (red[4] + red[5] + red[6] + red[7]) * (1.f / 1024.f);
    float rs = rsqrtf(var + 1e-5f);
    float4 gv = ((const float4*)g)[t];
    float4 bv = ((const float4*)be)[t];
    ushort4 o4;
    o4.x = f2bf(d0 * rs * gv.x + bv.x);
    o4.y = f2bf(d1 * rs * gv.y + bv.y);
    o4.z = f2bf(d2 * rs * gv.z + bv.z);
    o4.w = f2bf(d3 * rs * gv.w + bv.w);
    ((ushort4*)X)[(size_t)row * 256 + t] = o4;
  } else {
    int wb = bid - M_;                       // 0..2047
    int k0 = (wb & 31) * 32, n0 = (wb >> 5) * 32;
    int rr = t >> 3, c4 = (t & 7) * 4;
    float4 v = *(const float4*)(W + (size_t)(k0 + rr) * TC_ + n0 + c4);
    tile[rr][c4] = v.x; tile[rr][c4 + 1] = v.y; tile[rr][c4 + 2] = v.z; tile[rr][c4 + 3] = v.w;
    __syncthreads();
    int n = t >> 3, k4 = (t & 7) * 4;
    ushort4 o;
    o.x = f2bf(tile[k4][n]);     o.y = f2bf(tile[k4 + 1][n]);
    o.z = f2bf(tile[k4 + 2][n]); o.w = f2bf(tile[k4 + 3][n]);
    *(ushort4*)(WT + (size_t)(n0 + n) * C_ + k0 + k4) = o;
  }
}

// ---------------- QK GEMM (MFMA bf16, BK=64: half the barriers) ----------------
// X[m][k] @ WT[n][k]^T -> QK bf16 [t][b][h][n][d]
// LDS rows 128B (64 bf16), 8 x 16B slots, XOR-swizzled by row&7 (k_attn-proven).
__global__ __launch_bounds__(256) void k_qk(const u16* __restrict__ X,
                                            const u16* __restrict__ WT,
                                            const float* __restrict__ bias,
                                            u16* __restrict__ QK) {
  __shared__ u16 As[128 * 64];   // 16 KB
  __shared__ u16 Bs[128 * 64];   // 16 KB
  int t = threadIdx.x, lane = t & 63, w = t >> 6;
  int wr = w >> 1, wc = w & 1;
  // XCD-aware swizzle: 2048 blocks, 8 XCDs, 256/XCD; bn-fast within XCD
  int bid = blockIdx.x;
  int swz = (bid & 7) * 256 + (bid >> 3);
  int rowA0 = (swz >> 4) * 128, colB0 = (swz & 15) * 128;
  int colbase = lane & 15, kslot = lane >> 4;

  f32x4 acc[4][4] = {};

  for (int k0 = 0; k0 < C_; k0 += 64) {
    __syncthreads();
    const u16* Xrow = X + (size_t)rowA0 * C_ + k0;
    const u16* Wrow = WT + (size_t)colB0 * C_ + k0;
    #pragma unroll
    for (int p = 0; p < 4; p++) {
      int o = p * 4096 + w * 1024 + lane * 16;  // linear LDS byte offset
      int row = o >> 7, slot = (o >> 4) & 7;
      int kb16 = slot ^ (row & 7);              // pre-swizzled global source
      const u16* gp = Xrow + (size_t)row * C_ + (kb16 << 3);
      __builtin_amdgcn_global_load_lds((const __attribute__((address_space(1))) void*)gp,
                                       (__attribute__((address_space(3))) void*)((char*)As + o),
                                       16, 0, 0);
    }
    #pragma unroll
    for (int p = 0; p < 4; p++) {
      int o = p * 4096 + w * 1024 + lane * 16;
      int row = o >> 7, slot = (o >> 4) & 7;
      int kb16 = slot ^ (row & 7);
      const u16* gp = Wrow + (size_t)row * C_ + (kb16 << 3);
      __builtin_amdgcn_global_load_lds((const __attribute__((address_space(1))) void*)gp,
                                       (__attribute__((address_space(3))) void*)((char*)Bs + o),
                                       16, 0, 0);
    }
    __syncthreads();
    #pragma unroll
    for (int kk = 0; kk < 2; kk++) {
      bf16x8 a[4], b[4];
      int ks = kslot + kk * 4;                  // global 16B k-chunk within row
      #pragma unroll
      for (int i = 0; i < 4; i++) {
        int row = wr * 64 + i * 16 + colbase;
        a[i] = *(const bf16x8*)((const char*)As + row * 128 + ((ks ^ (row & 7)) << 4));
      }
      #pragma unroll
      for (int j = 0; j < 4; j++) {
        int col = wc * 64 + j * 16 + colbase;
        b[j] = *(const bf16x8*)((const char*)Bs + col * 128 + ((ks ^ (col & 7)) << 4));
      }
      #pragma unroll
      for (int i = 0; i < 4; i++)
        #pragma unroll
        for (int j = 0; j < 4; j++)
          acc[i][j] = __builtin_amdgcn_mfma_f32_16x16x32_bf16(a[i], b[j], acc[i][j], 0, 0, 0);
    }
  }

  // epilogue: +bias, f2bf, scatter to [t][b][h][n][d]
  float bv[4];
  #pragma unroll
  for (int j = 0; j < 4; j++) bv[j] = bias[colB0 + wc * 64 + j * 16 + colbase];
  #pragma unroll
  for (int i = 0; i < 4; i++) {
    #pragma unroll
    for (int j = 0; j < 4; j++) {
      int col = colB0 + wc * 64 + j * 16 + colbase;
      int tsel = col >> 10, rem = col & 1023;
      int h = rem >> 6, dd = rem & 63;
      #pragma unroll
      for (int q = 0; q < 4; q++) {
        int m = rowA0 + wr * 64 + i * 16 + (lane >> 4) * 4 + q;
        int b2 = m >> 9, n = m & 511;
        QK[(((size_t)(tsel * B_ + b2) * H_ + h) * N_ + n) * D_ + dd] = f2bf(acc[i][j][q] + bv[j]);
      }
    }
  }
}

// ---- attention (round-10 verified: MFMA two-pass, K staged in LDS) ----
__global__ __launch_bounds__(512) void k_attn(const u16* __restrict__ QK,
                                              float* __restrict__ CWg) {
  __shared__ u16 Ks[N_ * D_];        // 64KB, rows 128B, 16B slots swizzled by row&7
  __shared__ float rsl[N_];          // 2KB reciprocal row sums
  int bh = blockIdx.x;
  const u16* qb = QK + (size_t)bh * (N_ * D_);
  const u16* kb = QK + (size_t)(B_ * H_ + bh) * (N_ * D_);
  int t = threadIdx.x, lane = t & 63, w = t >> 6;
  int colbase = lane & 15, kslot = lane >> 4;

  #pragma unroll
  for (int i2 = 0; i2 < 8; i2++) {
    int vec = t + i2 * 512;                 // 0..4095 16B-granules
    int c = vec >> 3, d8 = vec & 7;
    uint4 pk = *(const uint4*)(kb + ((size_t)c << 6) + (d8 << 3));
    *(uint4*)((char*)Ks + c * 128 + ((d8 ^ (c & 7)) << 4)) = pk;
  }
  __syncthreads();

  // ---- pass 1: row-sum reciprocals for this wave's 4 q-tiles ----
  #pragma unroll 1
  for (int si = 0; si < 4; si++) {
    int n0 = (w * 4 + si) * 16;
    bf16x8 aq0 = *(const bf16x8*)(qb + (size_t)(n0 + colbase) * 64 + kslot * 8);
    bf16x8 aq1 = *(const bf16x8*)(qb + (size_t)(n0 + colbase) * 64 + 32 + kslot * 8);
    float sj[4] = {0.f, 0.f, 0.f, 0.f};
    #pragma unroll 4
    for (int tl = 0; tl < 32; tl++) {
      int m = tl * 16 + colbase;
      const char* kr = (const char*)Ks + m * 128;
      bf16x8 bk0 = *(const bf16x8*)(kr + ((kslot ^ (m & 7)) << 4));
      bf16x8 bk1 = *(const bf16x8*)(kr + (((kslot + 4) ^ (m & 7)) << 4));
      f32x4 z = {0.f, 0.f, 0.f, 0.f};
      z = __builtin_amdgcn_mfma_f32_16x16x32_bf16(aq0, bk0, z, 0, 0, 0);
      z = __builtin_amdgcn_mfma_f32_16x16x32_bf16(aq1, bk1, z, 0, 0, 0);
      #pragma unroll
      for (int q = 0; q < 4; q++) sj[q] += __expf(z[q] * 0.125f);
    }
    #pragma unroll
    for (int q = 0; q < 4; q++) {
      sj[q] += __shfl_xor(sj[q], 1);
      sj[q] += __shfl_xor(sj[q], 2);
      sj[q] += __shfl_xor(sj[q], 4);
      sj[q] += __shfl_xor(sj[q], 8);
    }
    if (colbase == 0) {
      #pragma unroll
      for (int q = 0; q < 4; q++) rsl[n0 + kslot * 4 + q] = 1.f / sj[q];
    }
  }
  __syncthreads();

  // ---- pass 2: hoist this wave's 8 K-fragments, stream q-tiles ----
  bf16x8 kf[4][2];
  #pragma unroll
  for (int ct = 0; ct < 4; ct++) {
    int m = (w * 4 + ct) * 16 + colbase;
    const char* kr = (const char*)Ks + m * 128;
    kf[ct][0] = *(const bf16x8*)(kr + ((kslot ^ (m & 7)) << 4));
    kf[ct][1] = *(const bf16x8*)(kr + (((kslot + 4) ^ (m & 7)) << 4));
  }
  f32x4 acc[4] = {};
  #pragma unroll 2
  for (int si = 0; si < 32; si++) {
    int n0 = si * 16;
    bf16x8 aq0 = *(const bf16x8*)(qb + (size_t)(n0 + colbase) * 64 + kslot * 8);
    bf16x8 aq1 = *(const bf16x8*)(qb + (size_t)(n0 + colbase) * 64 + 32 + kslot * 8);
    float rr = rsl[n0 + colbase];          // this lane's output column n
    #pragma unroll
    for (int ct = 0; ct < 4; ct++) {
      f32x4 z = {0.f, 0.f, 0.f, 0.f};
      z = __builtin_amdgcn_mfma_f32_16x16x32_bf16(kf[ct][0], aq0, z, 0, 0, 0);
      z = __builtin_amdgcn_mfma_f32_16x16x32_bf16(kf[ct][1], aq1, z, 0, 0, 0);
      #pragma unroll
      for (int q = 0; q < 4; q++) acc[ct][q] += __expf(z[q] * 0.125f) * rr;
    }
  }
  #pragma unroll
  for (int ct = 0; ct < 4; ct++) {
    #pragma unroll
    for (int q = 0; q < 4; q++) {
      float v = acc[ct][q];
      v += __shfl_xor(v, 1);
      v += __shfl_xor(v, 2);
      v += __shfl_xor(v, 4);
      v += __shfl_xor(v, 8);
      if (colbase == 0)
        CWg[(size_t)bh * 512 + (w * 4 + ct) * 16 + kslot * 4 + q] = v * (1.f / 512.f);
    }
  }
}

// ---------------- Y2[mh,b,h,k] = sum_{m in half} CW[b,h,m] * X[b,m,k] ----------------
__global__ __launch_bounds__(256) void k_ybar(const float* __restrict__ CW,
                                              const u16* __restrict__ X,
                                              float* __restrict__ Y2) {
  __shared__ float cwl[256][17];   // [m][h], padded
  int bid = blockIdx.x;            // 512 = 8 kb * 32 b * 2 mh
  int kb = bid & 7, b = (bid >> 3) & 31, mh = bid >> 8;
  int t = threadIdx.x;
  int h = t >> 4, ks = t & 15;
  int m0 = mh * 256;
  #pragma unroll
  for (int i = 0; i < 16; i++)
    cwl[t][i] = CW[(size_t)(b * 16 + i) * 512 + m0 + t];   // coalesced per i
  __syncthreads();
  int kc = kb * 128 + ks * 8;
  const u16* Xb = X + ((size_t)b * 512 + m0) * 1024 + kc;
  float acc[8] = {};
  #pragma unroll 4
  for (int m = 0; m < 256; m++) {
    float wgt = cwl[m][h];
    ushort8 xv = *(const ushort8*)(Xb + (size_t)m * 1024);
    #pragma unroll
    for (int e = 0; e < 8; e++) acc[e] = fmaf(wgt, bfl((u32)xv[e]), acc[e]);
  }
  float* yp = Y2 + ((size_t)(mh * 32 + b) * 16 + h) * 1024 + kc;
  *(float4*)yp = *(float4*)&acc[0];
  *(float4*)(yp + 4) = *(float4*)&acc[4];
}

// ---------------- ybar = mean; z[c'] = ybar[h(c')]·Wv[:,c'] + bv[c'] ----------------
__global__ __launch_bounds__(256) void k_head0(const float* __restrict__ y,
                                               const float* __restrict__ qkvw,
                                               const float* __restrict__ qkvb,
                                               float* __restrict__ z) {
  __shared__ float yb[1024];
  __shared__ float part[4][64];
  int h = blockIdx.x, t = threadIdx.x;
  for (int k = t; k < 1024; k += 256) {
    float s = 0.f;
    #pragma unroll 4
    for (int p = 0; p < 64; p++) s += y[((size_t)(p * 16 + h) << 10) + k];
    yb[k] = s * (1.f / 32.f);
  }
  __syncthreads();
  int col = t & 63, q = t >> 6;
  float acc = 0.f;
  for (int k = q * 256; k < q * 256 + 256; k++)
    acc = fmaf(yb[k], qkvw[(size_t)k * TC_ + 2048 + h * 64 + col], acc);
  part[q][col] = acc;
  __syncthreads();
  if (t < 64)
    z[h * 64 + t] = part[0][t] + part[1][t] + part[2][t] + part[3][t] + qkvb[2048 + h * 64 + t];
}

// ---------------- mu = 2*(z @ proj_w + proj_b)  [32 blocks x 32 cols] ----------------
__global__ __launch_bounds__(256) void k_head1(const float* __restrict__ z,
                                               const float* __restrict__ pw,
                                               const float* __restrict__ pb,
                                               float* __restrict__ mu) {
  __shared__ float zs[1024];
  __shared__ float part[8][32];
  int t = threadIdx.x;
  for (int j = t; j < 1024; j += 256) zs[j] = z[j];
  __syncthreads();
  int col = blockIdx.x * 32 + (t & 31), q = t >> 5;
  float acc = 0.f;
  #pragma unroll 4
  for (int k = q * 128; k < q * 128 + 128; k++)
    acc = fmaf(zs[k], pw[(size_t)k * 1024 + col], acc);
  part[q][t & 31] = acc;
  __syncthreads();
  if (t < 32) {
    float s = pb[blockIdx.x * 32 + t];
    #pragma unroll
    for (int p = 0; p < 8; p++) s += part[p][t];
    mu[blockIdx.x * 32 + t] = 2.f * s;
  }
}

// ---------------- sigma = 0.1 + 0.9*sigmoid(mu@sig_w + sig_b)  [32 blocks] ----------------
__global__ __launch_bounds__(256) void k_head2(const float* __restrict__ mu,
                                               const float* __restrict__ sw,
                                               const float* __restrict__ sb,
                                               float* __restrict__ sig) {
  __shared__ float ms[1024];
  __shared__ float part[8][32];
  int t = threadIdx.x;
  for (int j = t; j < 1024; j += 256) ms[j] = mu[j];
  __syncthreads();
  int col = blockIdx.x * 32 + (t & 31), q = t >> 5;
  float acc = 0.f;
  #pragma unroll 4
  for (int k = q * 128; k < q * 128 + 128; k++)
    acc = fmaf(ms[k], sw[(size_t)k * 1024 + col], acc);
  part[q][t & 31] = acc;
  __syncthreads();
  if (t < 32) {
    float s = sb[blockIdx.x * 32 + t];
    #pragma unroll
    for (int p = 0; p < 8; p++) s += part[p][t];
    sig[blockIdx.x * 32 + t] = 0.1f + 0.9f / (1.f + expf(-s));
  }
}

// ---------------- eps (JAX threefry, partitionable) + latent ----------------
__device__ __forceinline__ uint2 threefry_0_42(u32 x0, u32 x1) {
  const u32 ks0 = 0u, ks1 = 42u, ks2 = 0x1BD11BF0u;
  x0 += ks0; x1 += ks1;
  #define RND(r) { x0 += x1; x1 = (x1 << r) | (x1 >> (32 - r)); x1 ^= x0; }
  RND(13) RND(15) RND(26) RND(6)   x0 += ks1; x1 += ks2 + 1u;
  RND(17) RND(29) RND(16) RND(24)  x0 += ks2; x1 += ks0 + 2u;
  RND(13) RND(15) RND(26) RND(6)   x0 += ks0; x1 += ks1 + 3u;
  RND(17) RND(29) RND(16) RND(24)  x0 += ks1; x1 += ks2 + 4u;
  RND(13) RND(15) RND(26) RND(6)   x0 += ks2; x1 += ks0 + 5u;
  #undef RND
  return make_uint2(x0, x1);
}

__device__ __forceinline__ float bits_to_normal(u32 bits) {
  u32 fb = (bits >> 9) | 0x3F800000u;
  float fl = __builtin_bit_cast(float, fb) - 1.0f;
  float u = __fmul_rn(fl, 2.0f);
  u = __fadd_rn(u, -0.99999994f);
  u = fmaxf(-0.99999994f, u);
  float x = u;
  float wv = -log1pf(-x * x);
  float p;
  if (wv < 5.0f) {
    wv -= 2.5f;
    p = 2.81022636e-08f;
    p = fmaf(p, wv, 3.43273939e-07f);
    p = fmaf(p, wv, -3.5233877e-06f);
    p = fmaf(p, wv, -4.39150654e-06f);
    p = fmaf(p, wv, 0.00021858087f);
    p = fmaf(p, wv, -0.00125372503f);
    p = fmaf(p, wv, -0.00417768164f);
    p = fmaf(p, wv, 0.246640727f);
    p = fmaf(p, wv, 1.50140941f);
  } else {
    wv = sqrtf(wv) - 3.0f;
    p = -0.000200214257f;
    p = fmaf(p, wv, 0.000100950558f);
    p = fmaf(p, wv, 0.00134934322f);
    p = fmaf(p, wv, -0.00367342844f);
    p = fmaf(p, wv, 0.00573950773f);
    p = fmaf(p, wv, -0.0076224613f);
    p = fmaf(p, wv, 0.00943887047f);
    p = fmaf(p, wv, 1.00167406f);
    p = fmaf(p, wv, 2.83297682f);
  }
  return 1.41421356f * (p * x);
}

__global__ __launch_bounds__(256) void k_latent(const float* __restrict__ mu,
                                                const float* __restrict__ sig,
                                                float* __restrict__ out) {
  u32 f = blockIdx.x * 256 + threadIdx.x;
  uint2 rb = threefry_0_42(0u, f);
  float eps = bits_to_normal(rb.x ^ rb.y);
  int c = f & 1023;
  out[f] = mu[c] + sig[c] * eps;
}

extern "C" void kernel_launch(void* const* d_in, const int* in_sizes, int n_in,
                              void* d_out, int out_size, void* d_ws, size_t ws_size,
                              hipStream_t stream) {
  const float* r    = (const float*)d_in[0];
  const float* lng  = (const float*)d_in[1];
  const float* lnb  = (const float*)d_in[2];
  const float* qkvw = (const float*)d_in[3];
  const float* qkvb = (const float*)d_in[4];
  const float* pw   = (const float*)d_in[5];
  const float* pb   = (const float*)d_in[6];
  const float* sw   = (const float*)d_in[7];
  const float* sb   = (const float*)d_in[8];
  float* out = (float*)d_out;

  u16* X   = (u16*)d_ws;                           // 32 MiB
  u16* QK  = X + (size_t)M_ * C_;                  // 64 MiB (2 planes: Q,K)
  u16* WT  = QK + (size_t)2 * M_ * C_;             // 4 MiB (bf16 [2048][1024])
  float* CW = (float*)(WT + (size_t)NQK_ * C_);    // 1 MiB (512*512 f32)
  float* Y2 = CW + (size_t)B_ * H_ * N_;           // 4 MiB (64*16*1024 f32)
  float* Z  = Y2 + (size_t)64 * H_ * C_;           // 4 KB
  float* MU  = Z + C_;
  float* SIG = MU + C_;

  k_pre<<<M_ + NQK_, 256, 0, stream>>>(r, lng, lnb, qkvw, X, WT);
  k_qk<<<M_ / 128 * (NQK_ / 128), 256, 0, stream>>>(X, WT, qkvb, QK);
  k_attn<<<B_ * H_, 512, 0, stream>>>(QK, CW);
  k_ybar<<<512, 256, 0, stream>>>(CW, X, Y2);
  k_head0<<<H_, 256, 0, stream>>>(Y2, qkvw, qkvb, Z);
  k_head1<<<32, 256, 0, stream>>>(Z, pw, pb, MU);
  k_head2<<<32, 256, 0, stream>>>(MU, sw, sb, SIG);
  k_latent<<<256, 256, 0, stream>>>(MU, SIG, out);
}

// Round 18
// 231.821 us; speedup vs baseline: 1.1322x; 1.1322x over previous
//
#include <hip/hip_runtime.h>

#define B_ 32
#define N_ 512
#define C_ 1024
#define H_ 16
#define D_ 64
#define TC_ 3072
#define NQK_ 2048
#define M_ (B_*N_)

typedef unsigned int u32;
typedef unsigned short u16;
typedef __attribute__((ext_vector_type(8))) unsigned short ushort8;
typedef __attribute__((ext_vector_type(8))) short bf16x8;   // 8 bf16 (4 VGPRs)
typedef __attribute__((ext_vector_type(4))) float f32x4;

__device__ __forceinline__ float bfl(u32 u){ return __builtin_bit_cast(float, u << 16); }
__device__ __forceinline__ u16 f2bf(float f){
  u32 u = __builtin_bit_cast(u32, f);
  u32 r = (u + 0x7FFFu + ((u >> 16) & 1u)) >> 16;
  return (u16)r;
}

// ------------- fused prelude: LN (blocks 0..16383) + W-transpose (16384..18431) -------------
__global__ __launch_bounds__(256) void k_pre(const float* __restrict__ r,
                                             const float* __restrict__ g,
                                             const float* __restrict__ be,
                                             const float* __restrict__ W,
                                             u16* __restrict__ X,
                                             u16* __restrict__ WT) {
  __shared__ float tile[32][33];     // wcvt path (ln path uses first 8 floats)
  int bid = blockIdx.x, t = threadIdx.x;
  if (bid < M_) {
    float* red = &tile[0][0];
    int row = bid;
    float4 v = ((const float4*)(r + (size_t)row * C_))[t];
    float s = (v.x + v.y) + (v.z + v.w);
    #pragma unroll
    for (int o = 32; o; o >>= 1) s += __shfl_xor(s, o);
    if ((t & 63) == 0) red[t >> 6] = s;
    __syncthreads();
    float mean = (red[0] + red[1] + red[2] + red[3]) * (1.f / 1024.f);
    float d0 = v.x - mean, d1 = v.y - mean, d2 = v.z - mean, d3 = v.w - mean;
    float q = d0*d0 + d1*d1 + d2*d2 + d3*d3;
    #pragma unroll
    for (int o = 32; o; o >>= 1) q += __shfl_xor(q, o);
    if ((t & 63) == 0) red[4 + (t >> 6)] = q;
    __syncthreads();
    float var = (red[4] + red[5] + red[6] + red[7]) * (1.f / 1024.f);
    float rs = rsqrtf(var + 1e-5f);
    float4 gv = ((const float4*)g)[t];
    float4 bv = ((const float4*)be)[t];
    ushort4 o4;
    o4.x = f2bf(d0 * rs * gv.x + bv.x);
    o4.y = f2bf(d1 * rs * gv.y + bv.y);
    o4.z = f2bf(d2 * rs * gv.z + bv.z);
    o4.w = f2bf(d3 * rs * gv.w + bv.w);
    ((ushort4*)X)[(size_t)row * 256 + t] = o4;
  } else {
    int wb = bid - M_;                       // 0..2047
    int k0 = (wb & 31) * 32, n0 = (wb >> 5) * 32;
    int rr = t >> 3, c4 = (t & 7) * 4;
    float4 v = *(const float4*)(W + (size_t)(k0 + rr) * TC_ + n0 + c4);
    tile[rr][c4] = v.x; tile[rr][c4 + 1] = v.y; tile[rr][c4 + 2] = v.z; tile[rr][c4 + 3] = v.w;
    __syncthreads();
    int n = t >> 3, k4 = (t & 7) * 4;
    ushort4 o;
    o.x = f2bf(tile[k4][n]);     o.y = f2bf(tile[k4 + 1][n]);
    o.z = f2bf(tile[k4 + 2][n]); o.w = f2bf(tile[k4 + 3][n]);
    *(ushort4*)(WT + (size_t)(n0 + n) * C_ + k0 + k4) = o;
  }
}

// ---------------- QK GEMM (MFMA bf16, round-10 verified structure, BK=32) ----------------
// X[m][k] @ WT[n][k]^T -> QK bf16 [t][b][h][n][d]
__global__ __launch_bounds__(256) void k_qk(const u16* __restrict__ X,
                                            const u16* __restrict__ WT,
                                            const float* __restrict__ bias,
                                            u16* __restrict__ QK) {
  __shared__ u16 As[128 * 32];   // rows 64B (32 bf16), 16B slots, XOR-swizzled by (row>>1)&3
  __shared__ u16 Bs[128 * 32];
  int t = threadIdx.x, lane = t & 63, w = t >> 6;
  int wr = w >> 1, wc = w & 1;
  // XCD-aware swizzle: 2048 blocks, 8 XCDs, 256/XCD; bn-fast within XCD
  int bid = blockIdx.x;
  int swz = (bid & 7) * 256 + (bid >> 3);
  int rowA0 = (swz >> 4) * 128, colB0 = (swz & 15) * 128;
  int colbase = lane & 15, kslot = lane >> 4;

  f32x4 acc[4][4] = {};

  for (int k0 = 0; k0 < C_; k0 += 32) {
    __syncthreads();
    const u16* Xrow = X + (size_t)rowA0 * C_ + k0;
    const u16* Wrow = WT + (size_t)colB0 * C_ + k0;
    #pragma unroll
    for (int p = 0; p < 2; p++) {
      int o = p * 4096 + w * 1024 + lane * 16;  // linear LDS byte offset
      int row = o >> 6, slot = (o >> 4) & 3;
      int kb16 = slot ^ ((row >> 1) & 3);       // pre-swizzled global source
      const u16* gp = Xrow + (size_t)row * C_ + (kb16 << 3);
      __builtin_amdgcn_global_load_lds((const __attribute__((address_space(1))) void*)gp,
                                       (__attribute__((address_space(3))) void*)((char*)As + o),
                                       16, 0, 0);
    }
    #pragma unroll
    for (int p = 0; p < 2; p++) {
      int o = p * 4096 + w * 1024 + lane * 16;
      int row = o >> 6, slot = (o >> 4) & 3;
      int kb16 = slot ^ ((row >> 1) & 3);
      const u16* gp = Wrow + (size_t)row * C_ + (kb16 << 3);
      __builtin_amdgcn_global_load_lds((const __attribute__((address_space(1))) void*)gp,
                                       (__attribute__((address_space(3))) void*)((char*)Bs + o),
                                       16, 0, 0);
    }
    __syncthreads();
    bf16x8 a[4], b[4];
    #pragma unroll
    for (int i = 0; i < 4; i++) {
      int row = wr * 64 + i * 16 + colbase;
      a[i] = *(const bf16x8*)((const char*)As + row * 64 + ((kslot ^ ((row >> 1) & 3)) << 4));
    }
    #pragma unroll
    for (int j = 0; j < 4; j++) {
      int col = wc * 64 + j * 16 + colbase;
      b[j] = *(const bf16x8*)((const char*)Bs + col * 64 + ((kslot ^ ((col >> 1) & 3)) << 4));
    }
    #pragma unroll
    for (int i = 0; i < 4; i++)
      #pragma unroll
      for (int j = 0; j < 4; j++)
        acc[i][j] = __builtin_amdgcn_mfma_f32_16x16x32_bf16(a[i], b[j], acc[i][j], 0, 0, 0);
  }

  // epilogue: +bias, f2bf, scatter to [t][b][h][n][d]
  float bv[4];
  #pragma unroll
  for (int j = 0; j < 4; j++) bv[j] = bias[colB0 + wc * 64 + j * 16 + colbase];
  #pragma unroll
  for (int i = 0; i < 4; i++) {
    #pragma unroll
    for (int j = 0; j < 4; j++) {
      int col = colB0 + wc * 64 + j * 16 + colbase;
      int tsel = col >> 10, rem = col & 1023;
      int h = rem >> 6, dd = rem & 63;
      #pragma unroll
      for (int q = 0; q < 4; q++) {
        int m = rowA0 + wr * 64 + i * 16 + (lane >> 4) * 4 + q;
        int b2 = m >> 9, n = m & 511;
        QK[(((size_t)(tsel * B_ + b2) * H_ + h) * N_ + n) * D_ + dd] = f2bf(acc[i][j][q] + bv[j]);
      }
    }
  }
}

// ---- attention (round-10 verified: MFMA two-pass, K staged in LDS) ----
__global__ __launch_bounds__(512) void k_attn(const u16* __restrict__ QK,
                                              float* __restrict__ CWg) {
  __shared__ u16 Ks[N_ * D_];        // 64KB, rows 128B, 16B slots swizzled by row&7
  __shared__ float rsl[N_];          // 2KB reciprocal row sums
  int bh = blockIdx.x;
  const u16* qb = QK + (size_t)bh * (N_ * D_);
  const u16* kb = QK + (size_t)(B_ * H_ + bh) * (N_ * D_);
  int t = threadIdx.x, lane = t & 63, w = t >> 6;
  int colbase = lane & 15, kslot = lane >> 4;

  #pragma unroll
  for (int i2 = 0; i2 < 8; i2++) {
    int vec = t + i2 * 512;                 // 0..4095 16B-granules
    int c = vec >> 3, d8 = vec & 7;
    uint4 pk = *(const uint4*)(kb + ((size_t)c << 6) + (d8 << 3));
    *(uint4*)((char*)Ks + c * 128 + ((d8 ^ (c & 7)) << 4)) = pk;
  }
  __syncthreads();

  // ---- pass 1: row-sum reciprocals for this wave's 4 q-tiles ----
  #pragma unroll 1
  for (int si = 0; si < 4; si++) {
    int n0 = (w * 4 + si) * 16;
    bf16x8 aq0 = *(const bf16x8*)(qb + (size_t)(n0 + colbase) * 64 + kslot * 8);
    bf16x8 aq1 = *(const bf16x8*)(qb + (size_t)(n0 + colbase) * 64 + 32 + kslot * 8);
    float sj[4] = {0.f, 0.f, 0.f, 0.f};
    #pragma unroll 4
    for (int tl = 0; tl < 32; tl++) {
      int m = tl * 16 + colbase;
      const char* kr = (const char*)Ks + m * 128;
      bf16x8 bk0 = *(const bf16x8*)(kr + ((kslot ^ (m & 7)) << 4));
      bf16x8 bk1 = *(const bf16x8*)(kr + (((kslot + 4) ^ (m & 7)) << 4));
      f32x4 z = {0.f, 0.f, 0.f, 0.f};
      z = __builtin_amdgcn_mfma_f32_16x16x32_bf16(aq0, bk0, z, 0, 0, 0);
      z = __builtin_amdgcn_mfma_f32_16x16x32_bf16(aq1, bk1, z, 0, 0, 0);
      #pragma unroll
      for (int q = 0; q < 4; q++) sj[q] += __expf(z[q] * 0.125f);
    }
    #pragma unroll
    for (int q = 0; q < 4; q++) {
      sj[q] += __shfl_xor(sj[q], 1);
      sj[q] += __shfl_xor(sj[q], 2);
      sj[q] += __shfl_xor(sj[q], 4);
      sj[q] += __shfl_xor(sj[q], 8);
    }
    if (colbase == 0) {
      #pragma unroll
      for (int q = 0; q < 4; q++) rsl[n0 + kslot * 4 + q] = 1.f / sj[q];
    }
  }
  __syncthreads();

  // ---- pass 2: hoist this wave's 8 K-fragments, stream q-tiles ----
  bf16x8 kf[4][2];
  #pragma unroll
  for (int ct = 0; ct < 4; ct++) {
    int m = (w * 4 + ct) * 16 + colbase;
    const char* kr = (const char*)Ks + m * 128;
    kf[ct][0] = *(const bf16x8*)(kr + ((kslot ^ (m & 7)) << 4));
    kf[ct][1] = *(const bf16x8*)(kr + (((kslot + 4) ^ (m & 7)) << 4));
  }
  f32x4 acc[4] = {};
  #pragma unroll 2
  for (int si = 0; si < 32; si++) {
    int n0 = si * 16;
    bf16x8 aq0 = *(const bf16x8*)(qb + (size_t)(n0 + colbase) * 64 + kslot * 8);
    bf16x8 aq1 = *(const bf16x8*)(qb + (size_t)(n0 + colbase) * 64 + 32 + kslot * 8);
    float rr = rsl[n0 + colbase];          // this lane's output column n
    #pragma unroll
    for (int ct = 0; ct < 4; ct++) {
      f32x4 z = {0.f, 0.f, 0.f, 0.f};
      z = __builtin_amdgcn_mfma_f32_16x16x32_bf16(kf[ct][0], aq0, z, 0, 0, 0);
      z = __builtin_amdgcn_mfma_f32_16x16x32_bf16(kf[ct][1], aq1, z, 0, 0, 0);
      #pragma unroll
      for (int q = 0; q < 4; q++) acc[ct][q] += __expf(z[q] * 0.125f) * rr;
    }
  }
  #pragma unroll
  for (int ct = 0; ct < 4; ct++) {
    #pragma unroll
    for (int q = 0; q < 4; q++) {
      float v = acc[ct][q];
      v += __shfl_xor(v, 1);
      v += __shfl_xor(v, 2);
      v += __shfl_xor(v, 4);
      v += __shfl_xor(v, 8);
      if (colbase == 0)
        CWg[(size_t)bh * 512 + (w * 4 + ct) * 16 + kslot * 4 + q] = v * (1.f / 512.f);
    }
  }
}

// ---------------- Y2[mh,b,h,k] = sum_{m in half} CW[b,h,m] * X[b,m,k] ----------------
__global__ __launch_bounds__(256) void k_ybar(const float* __restrict__ CW,
                                              const u16* __restrict__ X,
                                              float* __restrict__ Y2) {
  __shared__ float cwl[256][17];   // [m][h], padded
  int bid = blockIdx.x;            // 512 = 8 kb * 32 b * 2 mh
  int kb = bid & 7, b = (bid >> 3) & 31, mh = bid >> 8;
  int t = threadIdx.x;
  int h = t >> 4, ks = t & 15;
  int m0 = mh * 256;
  #pragma unroll
  for (int i = 0; i < 16; i++)
    cwl[t][i] = CW[(size_t)(b * 16 + i) * 512 + m0 + t];   // coalesced per i
  __syncthreads();
  int kc = kb * 128 + ks * 8;
  const u16* Xb = X + ((size_t)b * 512 + m0) * 1024 + kc;
  float acc[8] = {};
  #pragma unroll 4
  for (int m = 0; m < 256; m++) {
    float wgt = cwl[m][h];
    ushort8 xv = *(const ushort8*)(Xb + (size_t)m * 1024);
    #pragma unroll
    for (int e = 0; e < 8; e++) acc[e] = fmaf(wgt, bfl((u32)xv[e]), acc[e]);
  }
  float* yp = Y2 + ((size_t)(mh * 32 + b) * 16 + h) * 1024 + kc;
  *(float4*)yp = *(float4*)&acc[0];
  *(float4*)(yp + 4) = *(float4*)&acc[4];
}

// ------- zpart[q][h*64+col] = sum_{k in q-slice} ybar[k] * Wv[k][col]  (64 blocks) -------
__global__ __launch_bounds__(256) void k_head0(const float* __restrict__ y,
                                               const float* __restrict__ qkvw,
                                               float* __restrict__ zp) {
  __shared__ float yb[256];
  __shared__ float part[4][64];
  int blk = blockIdx.x;          // 64 = h*4 + q
  int h = blk >> 2, q = blk & 3;
  int t = threadIdx.x;
  int k0 = q * 256;
  {
    float s = 0.f;
    int k = k0 + t;
    #pragma unroll 8
    for (int p = 0; p < 64; p++) s += y[((size_t)(p * 16 + h) << 10) + k];
    yb[t] = s * (1.f / 32.f);
  }
  __syncthreads();
  int col = t & 63, g = t >> 6;   // 4 k-groups of 64
  float acc = 0.f;
  #pragma unroll 8
  for (int kk = 0; kk < 64; kk++) {
    int k = g * 64 + kk;
    acc = fmaf(yb[k], qkvw[(size_t)(k0 + k) * TC_ + 2048 + h * 64 + col], acc);
  }
  part[g][col] = acc;
  __syncthreads();
  if (t < 64)
    zp[(size_t)q * 1024 + h * 64 + t] = part[0][t] + part[1][t] + part[2][t] + part[3][t];
}

// ---------------- mu = 2*((Σq zp + bv) @ proj_w + proj_b)  [32 blocks x 32 cols] ----------------
__global__ __launch_bounds__(256) void k_head1(const float* __restrict__ zp,
                                               const float* __restrict__ qkvb,
                                               const float* __restrict__ pw,
                                               const float* __restrict__ pb,
                                               float* __restrict__ mu) {
  __shared__ float zs[1024];
  __shared__ float part[8][32];
  int t = threadIdx.x;
  for (int j = t; j < 1024; j += 256)
    zs[j] = zp[j] + zp[1024 + j] + zp[2048 + j] + zp[3072 + j] + qkvb[2048 + j];
  __syncthreads();
  int col = blockIdx.x * 32 + (t & 31), q = t >> 5;
  float acc = 0.f;
  #pragma unroll 4
  for (int k = q * 128; k < q * 128 + 128; k++)
    acc = fmaf(zs[k], pw[(size_t)k * 1024 + col], acc);
  part[q][t & 31] = acc;
  __syncthreads();
  if (t < 32) {
    float s = pb[blockIdx.x * 32 + t];
    #pragma unroll
    for (int p = 0; p < 8; p++) s += part[p][t];
    mu[blockIdx.x * 32 + t] = 2.f * s;
  }
}

// ---------------- eps (JAX threefry, partitionable) ----------------
__device__ __forceinline__ uint2 threefry_0_42(u32 x0, u32 x1) {
  const u32 ks0 = 0u, ks1 = 42u, ks2 = 0x1BD11BF0u;
  x0 += ks0; x1 += ks1;
  #define RND(r) { x0 += x1; x1 = (x1 << r) | (x1 >> (32 - r)); x1 ^= x0; }
  RND(13) RND(15) RND(26) RND(6)   x0 += ks1; x1 += ks2 + 1u;
  RND(17) RND(29) RND(16) RND(24)  x0 += ks2; x1 += ks0 + 2u;
  RND(13) RND(15) RND(26) RND(6)   x0 += ks0; x1 += ks1 + 3u;
  RND(17) RND(29) RND(16) RND(24)  x0 += ks1; x1 += ks2 + 4u;
  RND(13) RND(15) RND(26) RND(6)   x0 += ks2; x1 += ks0 + 5u;
  #undef RND
  return make_uint2(x0, x1);
}

__device__ __forceinline__ float bits_to_normal(u32 bits) {
  u32 fb = (bits >> 9) | 0x3F800000u;
  float fl = __builtin_bit_cast(float, fb) - 1.0f;
  float u = __fmul_rn(fl, 2.0f);
  u = __fadd_rn(u, -0.99999994f);
  u = fmaxf(-0.99999994f, u);
  float x = u;
  float wv = -log1pf(-x * x);
  float p;
  if (wv < 5.0f) {
    wv -= 2.5f;
    p = 2.81022636e-08f;
    p = fmaf(p, wv, 3.43273939e-07f);
    p = fmaf(p, wv, -3.5233877e-06f);
    p = fmaf(p, wv, -4.39150654e-06f);
    p = fmaf(p, wv, 0.00021858087f);
    p = fmaf(p, wv, -0.00125372503f);
    p = fmaf(p, wv, -0.00417768164f);
    p = fmaf(p, wv, 0.246640727f);
    p = fmaf(p, wv, 1.50140941f);
  } else {
    wv = sqrtf(wv) - 3.0f;
    p = -0.000200214257f;
    p = fmaf(p, wv, 0.000100950558f);
    p = fmaf(p, wv, 0.00134934322f);
    p = fmaf(p, wv, -0.00367342844f);
    p = fmaf(p, wv, 0.00573950773f);
    p = fmaf(p, wv, -0.0076224613f);
    p = fmaf(p, wv, 0.00943887047f);
    p = fmaf(p, wv, 1.00167406f);
    p = fmaf(p, wv, 2.83297682f);
  }
  return 1.41421356f * (p * x);
}

// ----- sigma = 0.1 + 0.9*sigmoid(mu@sig_w + sig_b), fused with latent write [32 blocks] -----
__global__ __launch_bounds__(256) void k_head2(const float* __restrict__ mu,
                                               const float* __restrict__ sw,
                                               const float* __restrict__ sb,
                                               float* __restrict__ out) {
  __shared__ float ms[1024];
  __shared__ float part[8][32];
  __shared__ float sigs[32];
  int t = threadIdx.x;
  for (int j = t; j < 1024; j += 256) ms[j] = mu[j];
  __syncthreads();
  int col = blockIdx.x * 32 + (t & 31), q = t >> 5;
  float acc = 0.f;
  #pragma unroll 4
  for (int k = q * 128; k < q * 128 + 128; k++)
    acc = fmaf(ms[k], sw[(size_t)k * 1024 + col], acc);
  part[q][t & 31] = acc;
  __syncthreads();
  if (t < 32) {
    float s = sb[blockIdx.x * 32 + t];
    #pragma unroll
    for (int p = 0; p < 8; p++) s += part[p][t];
    sigs[t] = 0.1f + 0.9f / (1.f + expf(-s));
  }
  __syncthreads();
  int c0 = blockIdx.x * 32;
  #pragma unroll
  for (int e = t; e < 64 * 32; e += 256) {
    int row = e >> 5, cc = e & 31;
    u32 f = (u32)row * 1024 + c0 + cc;
    uint2 rb = threefry_0_42(0u, f);
    float eps = bits_to_normal(rb.x ^ rb.y);
    out[f] = ms[c0 + cc] + sigs[cc] * eps;
  }
}

extern "C" void kernel_launch(void* const* d_in, const int* in_sizes, int n_in,
                              void* d_out, int out_size, void* d_ws, size_t ws_size,
                              hipStream_t stream) {
  const float* r    = (const float*)d_in[0];
  const float* lng  = (const float*)d_in[1];
  const float* lnb  = (const float*)d_in[2];
  const float* qkvw = (const float*)d_in[3];
  const float* qkvb = (const float*)d_in[4];
  const float* pw   = (const float*)d_in[5];
  const float* pb   = (const float*)d_in[6];
  const float* sw   = (const float*)d_in[7];
  const float* sb   = (const float*)d_in[8];
  float* out = (float*)d_out;

  u16* X   = (u16*)d_ws;                           // 32 MiB
  u16* QK  = X + (size_t)M_ * C_;                  // 64 MiB (2 planes: Q,K)
  u16* WT  = QK + (size_t)2 * M_ * C_;             // 4 MiB (bf16 [2048][1024])
  float* CW = (float*)(WT + (size_t)NQK_ * C_);    // 1 MiB (512*512 f32)
  float* Y2 = CW + (size_t)B_ * H_ * N_;           // 4 MiB (64*16*1024 f32)
  float* ZP = Y2 + (size_t)64 * H_ * C_;           // 16 KB (4*1024 partials)
  float* MU = ZP + 4 * C_;                         // 4 KB

  k_pre<<<M_ + NQK_, 256, 0, stream>>>(r, lng, lnb, qkvw, X, WT);
  k_qk<<<M_ / 128 * (NQK_ / 128), 256, 0, stream>>>(X, WT, qkvb, QK);
  k_attn<<<B_ * H_, 512, 0, stream>>>(QK, CW);
  k_ybar<<<512, 256, 0, stream>>>(CW, X, Y2);
  k_head0<<<64, 256, 0, stream>>>(Y2, qkvw, ZP);
  k_head1<<<32, 256, 0, stream>>>(ZP, qkvb, pw, pb, MU);
  k_head2<<<32, 256, 0, stream>>>(MU, sw, sb, out);
}

// Round 19
// 225.916 us; speedup vs baseline: 1.1618x; 1.0261x over previous
//
#include <hip/hip_runtime.h>

#define B_ 32
#define N_ 512
#define C_ 1024
#define H_ 16
#define D_ 64
#define TC_ 3072
#define NQK_ 2048
#define M_ (B_*N_)

typedef unsigned int u32;
typedef unsigned short u16;
typedef __attribute__((ext_vector_type(8))) unsigned short ushort8;
typedef __attribute__((ext_vector_type(8))) short bf16x8;   // 8 bf16 (4 VGPRs)
typedef __attribute__((ext_vector_type(4))) float f32x4;

__device__ __forceinline__ float bfl(u32 u){ return __builtin_bit_cast(float, u << 16); }
__device__ __forceinline__ u16 f2bf(float f){
  u32 u = __builtin_bit_cast(u32, f);
  u32 r = (u + 0x7FFFu + ((u >> 16) & 1u)) >> 16;
  return (u16)r;
}

#define FENCE() asm volatile("" ::: "memory")
#define RAWBAR() { FENCE(); __builtin_amdgcn_s_barrier(); FENCE(); }
template<int N> __device__ __forceinline__ void vmwait() {
  asm volatile("s_waitcnt vmcnt(%0)" :: "n"(N) : "memory");
}

// ------------- fused prelude: LN (blocks 0..16383) + W-transpose (16384..18431) -------------
__global__ __launch_bounds__(256) void k_pre(const float* __restrict__ r,
                                             const float* __restrict__ g,
                                             const float* __restrict__ be,
                                             const float* __restrict__ W,
                                             u16* __restrict__ X,
                                             u16* __restrict__ WT) {
  __shared__ float tile[32][33];     // wcvt path (ln path uses first 8 floats)
  int bid = blockIdx.x, t = threadIdx.x;
  if (bid < M_) {
    float* red = &tile[0][0];
    int row = bid;
    float4 v = ((const float4*)(r + (size_t)row * C_))[t];
    float s = (v.x + v.y) + (v.z + v.w);
    #pragma unroll
    for (int o = 32; o; o >>= 1) s += __shfl_xor(s, o);
    if ((t & 63) == 0) red[t >> 6] = s;
    __syncthreads();
    float mean = (red[0] + red[1] + red[2] + red[3]) * (1.f / 1024.f);
    float d0 = v.x - mean, d1 = v.y - mean, d2 = v.z - mean, d3 = v.w - mean;
    float q = d0*d0 + d1*d1 + d2*d2 + d3*d3;
    #pragma unroll
    for (int o = 32; o; o >>= 1) q += __shfl_xor(q, o);
    if ((t & 63) == 0) red[4 + (t >> 6)] = q;
    __syncthreads();
    float var = (red[4] + red[5] + red[6] + red[7]) * (1.f / 1024.f);
    float rs = rsqrtf(var + 1e-5f);
    float4 gv = ((const float4*)g)[t];
    float4 bv = ((const float4*)be)[t];
    ushort4 o4;
    o4.x = f2bf(d0 * rs * gv.x + bv.x);
    o4.y = f2bf(d1 * rs * gv.y + bv.y);
    o4.z = f2bf(d2 * rs * gv.z + bv.z);
    o4.w = f2bf(d3 * rs * gv.w + bv.w);
    ((ushort4*)X)[(size_t)row * 256 + t] = o4;
  } else {
    int wb = bid - M_;                       // 0..2047
    int k0 = (wb & 31) * 32, n0 = (wb >> 5) * 32;
    int rr = t >> 3, c4 = (t & 7) * 4;
    float4 v = *(const float4*)(W + (size_t)(k0 + rr) * TC_ + n0 + c4);
    tile[rr][c4] = v.x; tile[rr][c4 + 1] = v.y; tile[rr][c4 + 2] = v.z; tile[rr][c4 + 3] = v.w;
    __syncthreads();
    int n = t >> 3, k4 = (t & 7) * 4;
    ushort4 o;
    o.x = f2bf(tile[k4][n]);     o.y = f2bf(tile[k4 + 1][n]);
    o.z = f2bf(tile[k4 + 2][n]); o.w = f2bf(tile[k4 + 3][n]);
    *(ushort4*)(WT + (size_t)(n0 + n) * C_ + k0 + k4) = o;
  }
}

// ---------------- QK GEMM (MFMA bf16, ring-3 counted-vmcnt pipeline) ----------------
// X[m][k] @ WT[n][k]^T -> QK bf16 [t][b][h][n][d]
// Prefetch distance 2, two raw barriers + vmcnt(8) per K-tile; NO vmcnt(0) drain
// in the main loop. Fully unrolled: all buffer indices / waits are static.
__global__ __launch_bounds__(256) void k_qk(const u16* __restrict__ X,
                                            const u16* __restrict__ WT,
                                            const float* __restrict__ bias,
                                            u16* __restrict__ QK) {
  __shared__ u16 As[3][128 * 32];  // 3 x 8 KB; rows 64B, 16B slots swizzled by (row>>1)&3
  __shared__ u16 Bs[3][128 * 32];  // 3 x 8 KB
  int t = threadIdx.x, lane = t & 63, w = t >> 6;
  int wr = w >> 1, wc = w & 1;
  // XCD-aware swizzle: 2048 blocks, 8 XCDs, 256/XCD; bn-fast within XCD
  int bid = blockIdx.x;
  int swz = (bid & 7) * 256 + (bid >> 3);
  int rowA0 = (swz >> 4) * 128, colB0 = (swz & 15) * 128;
  int colbase = lane & 15, kslot = lane >> 4;

  f32x4 acc[4][4] = {};

  // per-thread staging geometry (static)
  int o0 = w * 1024 + lane * 16;             // p=0 byte offset
  int o1 = 4096 + w * 1024 + lane * 16;      // p=1 byte offset
  int r0 = o0 >> 6, s0 = (o0 >> 4) & 3, kb0 = s0 ^ ((r0 >> 1) & 3);
  int r1 = o1 >> 6, s1 = (o1 >> 4) & 3, kb1 = s1 ^ ((r1 >> 1) & 3);

#define PF(buf, kt_) {                                                                 \
    const u16* Xr = X + (size_t)rowA0 * C_ + (kt_) * 32;                               \
    const u16* Wr = WT + (size_t)colB0 * C_ + (kt_) * 32;                              \
    __builtin_amdgcn_global_load_lds(                                                  \
      (const __attribute__((address_space(1))) void*)(Xr + (size_t)r0 * C_ + (kb0 << 3)), \
      (__attribute__((address_space(3))) void*)((char*)As[buf] + o0), 16, 0, 0);       \
    __builtin_amdgcn_global_load_lds(                                                  \
      (const __attribute__((address_space(1))) void*)(Xr + (size_t)r1 * C_ + (kb1 << 3)), \
      (__attribute__((address_space(3))) void*)((char*)As[buf] + o1), 16, 0, 0);       \
    __builtin_amdgcn_global_load_lds(                                                  \
      (const __attribute__((address_space(1))) void*)(Wr + (size_t)r0 * C_ + (kb0 << 3)), \
      (__attribute__((address_space(3))) void*)((char*)Bs[buf] + o0), 16, 0, 0);       \
    __builtin_amdgcn_global_load_lds(                                                  \
      (const __attribute__((address_space(1))) void*)(Wr + (size_t)r1 * C_ + (kb1 << 3)), \
      (__attribute__((address_space(3))) void*)((char*)Bs[buf] + o1), 16, 0, 0);       \
  }

  PF(0, 0);
  PF(1, 1);

  #pragma unroll
  for (int kt = 0; kt < 32; kt++) {
    RAWBAR();                                // A: compute(kt-1) reads retired everywhere
    if (kt + 2 < 32) PF((kt + 2) % 3, kt + 2);
    if (kt + 2 < 32)      vmwait<8>();       // my pf(kt) landed; 8 newer stay in flight
    else if (kt + 1 < 32) vmwait<4>();
    else                  vmwait<0>();
    RAWBAR();                                // B: ALL waves' pf(kt) landed
    const int buf = kt % 3;
    bf16x8 a[4], b[4];
    #pragma unroll
    for (int i = 0; i < 4; i++) {
      int row = wr * 64 + i * 16 + colbase;
      a[i] = *(const bf16x8*)((const char*)As[buf] + row * 64 + ((kslot ^ ((row >> 1) & 3)) << 4));
    }
    #pragma unroll
    for (int j = 0; j < 4; j++) {
      int col = wc * 64 + j * 16 + colbase;
      b[j] = *(const bf16x8*)((const char*)Bs[buf] + col * 64 + ((kslot ^ ((col >> 1) & 3)) << 4));
    }
    #pragma unroll
    for (int i = 0; i < 4; i++)
      #pragma unroll
      for (int j = 0; j < 4; j++)
        acc[i][j] = __builtin_amdgcn_mfma_f32_16x16x32_bf16(a[i], b[j], acc[i][j], 0, 0, 0);
  }
#undef PF

  // epilogue: +bias, f2bf, scatter to [t][b][h][n][d]
  float bv[4];
  #pragma unroll
  for (int j = 0; j < 4; j++) bv[j] = bias[colB0 + wc * 64 + j * 16 + colbase];
  #pragma unroll
  for (int i = 0; i < 4; i++) {
    #pragma unroll
    for (int j = 0; j < 4; j++) {
      int col = colB0 + wc * 64 + j * 16 + colbase;
      int tsel = col >> 10, rem = col & 1023;
      int h = rem >> 6, dd = rem & 63;
      #pragma unroll
      for (int q = 0; q < 4; q++) {
        int m = rowA0 + wr * 64 + i * 16 + (lane >> 4) * 4 + q;
        int b2 = m >> 9, n = m & 511;
        QK[(((size_t)(tsel * B_ + b2) * H_ + h) * N_ + n) * D_ + dd] = f2bf(acc[i][j][q] + bv[j]);
      }
    }
  }
}

// ---- attention (round-10 verified: MFMA two-pass, K staged in LDS) ----
__global__ __launch_bounds__(512) void k_attn(const u16* __restrict__ QK,
                                              float* __restrict__ CWg) {
  __shared__ u16 Ks[N_ * D_];        // 64KB, rows 128B, 16B slots swizzled by row&7
  __shared__ float rsl[N_];          // 2KB reciprocal row sums
  int bh = blockIdx.x;
  const u16* qb = QK + (size_t)bh * (N_ * D_);
  const u16* kb = QK + (size_t)(B_ * H_ + bh) * (N_ * D_);
  int t = threadIdx.x, lane = t & 63, w = t >> 6;
  int colbase = lane & 15, kslot = lane >> 4;

  #pragma unroll
  for (int i2 = 0; i2 < 8; i2++) {
    int vec = t + i2 * 512;                 // 0..4095 16B-granules
    int c = vec >> 3, d8 = vec & 7;
    uint4 pk = *(const uint4*)(kb + ((size_t)c << 6) + (d8 << 3));
    *(uint4*)((char*)Ks + c * 128 + ((d8 ^ (c & 7)) << 4)) = pk;
  }
  __syncthreads();

  // ---- pass 1: row-sum reciprocals for this wave's 4 q-tiles ----
  #pragma unroll 1
  for (int si = 0; si < 4; si++) {
    int n0 = (w * 4 + si) * 16;
    bf16x8 aq0 = *(const bf16x8*)(qb + (size_t)(n0 + colbase) * 64 + kslot * 8);
    bf16x8 aq1 = *(const bf16x8*)(qb + (size_t)(n0 + colbase) * 64 + 32 + kslot * 8);
    float sj[4] = {0.f, 0.f, 0.f, 0.f};
    #pragma unroll 4
    for (int tl = 0; tl < 32; tl++) {
      int m = tl * 16 + colbase;
      const char* kr = (const char*)Ks + m * 128;
      bf16x8 bk0 = *(const bf16x8*)(kr + ((kslot ^ (m & 7)) << 4));
      bf16x8 bk1 = *(const bf16x8*)(kr + (((kslot + 4) ^ (m & 7)) << 4));
      f32x4 z = {0.f, 0.f, 0.f, 0.f};
      z = __builtin_amdgcn_mfma_f32_16x16x32_bf16(aq0, bk0, z, 0, 0, 0);
      z = __builtin_amdgcn_mfma_f32_16x16x32_bf16(aq1, bk1, z, 0, 0, 0);
      #pragma unroll
      for (int q = 0; q < 4; q++) sj[q] += __expf(z[q] * 0.125f);
    }
    #pragma unroll
    for (int q = 0; q < 4; q++) {
      sj[q] += __shfl_xor(sj[q], 1);
      sj[q] += __shfl_xor(sj[q], 2);
      sj[q] += __shfl_xor(sj[q], 4);
      sj[q] += __shfl_xor(sj[q], 8);
    }
    if (colbase == 0) {
      #pragma unroll
      for (int q = 0; q < 4; q++) rsl[n0 + kslot * 4 + q] = 1.f / sj[q];
    }
  }
  __syncthreads();

  // ---- pass 2: hoist this wave's 8 K-fragments, stream q-tiles ----
  bf16x8 kf[4][2];
  #pragma unroll
  for (int ct = 0; ct < 4; ct++) {
    int m = (w * 4 + ct) * 16 + colbase;
    const char* kr = (const char*)Ks + m * 128;
    kf[ct][0] = *(const bf16x8*)(kr + ((kslot ^ (m & 7)) << 4));
    kf[ct][1] = *(const bf16x8*)(kr + (((kslot + 4) ^ (m & 7)) << 4));
  }
  f32x4 acc[4] = {};
  #pragma unroll 2
  for (int si = 0; si < 32; si++) {
    int n0 = si * 16;
    bf16x8 aq0 = *(const bf16x8*)(qb + (size_t)(n0 + colbase) * 64 + kslot * 8);
    bf16x8 aq1 = *(const bf16x8*)(qb + (size_t)(n0 + colbase) * 64 + 32 + kslot * 8);
    float rr = rsl[n0 + colbase];          // this lane's output column n
    #pragma unroll
    for (int ct = 0; ct < 4; ct++) {
      f32x4 z = {0.f, 0.f, 0.f, 0.f};
      z = __builtin_amdgcn_mfma_f32_16x16x32_bf16(kf[ct][0], aq0, z, 0, 0, 0);
      z = __builtin_amdgcn_mfma_f32_16x16x32_bf16(kf[ct][1], aq1, z, 0, 0, 0);
      #pragma unroll
      for (int q = 0; q < 4; q++) acc[ct][q] += __expf(z[q] * 0.125f) * rr;
    }
  }
  #pragma unroll
  for (int ct = 0; ct < 4; ct++) {
    #pragma unroll
    for (int q = 0; q < 4; q++) {
      float v = acc[ct][q];
      v += __shfl_xor(v, 1);
      v += __shfl_xor(v, 2);
      v += __shfl_xor(v, 4);
      v += __shfl_xor(v, 8);
      if (colbase == 0)
        CWg[(size_t)bh * 512 + (w * 4 + ct) * 16 + kslot * 4 + q] = v * (1.f / 512.f);
    }
  }
}

// ---------------- Y2[mh,b,h,k] = sum_{m in half} CW[b,h,m] * X[b,m,k] ----------------
__global__ __launch_bounds__(256) void k_ybar(const float* __restrict__ CW,
                                              const u16* __restrict__ X,
                                              float* __restrict__ Y2) {
  __shared__ float cwl[256][17];   // [m][h], padded
  int bid = blockIdx.x;            // 512 = 8 kb * 32 b * 2 mh
  int kb = bid & 7, b = (bid >> 3) & 31, mh = bid >> 8;
  int t = threadIdx.x;
  int h = t >> 4, ks = t & 15;
  int m0 = mh * 256;
  #pragma unroll
  for (int i = 0; i < 16; i++)
    cwl[t][i] = CW[(size_t)(b * 16 + i) * 512 + m0 + t];   // coalesced per i
  __syncthreads();
  int kc = kb * 128 + ks * 8;
  const u16* Xb = X + ((size_t)b * 512 + m0) * 1024 + kc;
  float acc[8] = {};
  #pragma unroll 4
  for (int m = 0; m < 256; m++) {
    float wgt = cwl[m][h];
    ushort8 xv = *(const ushort8*)(Xb + (size_t)m * 1024);
    #pragma unroll
    for (int e = 0; e < 8; e++) acc[e] = fmaf(wgt, bfl((u32)xv[e]), acc[e]);
  }
  float* yp = Y2 + ((size_t)(mh * 32 + b) * 16 + h) * 1024 + kc;
  *(float4*)yp = *(float4*)&acc[0];
  *(float4*)(yp + 4) = *(float4*)&acc[4];
}

// ------- zpart[q][h*64+col] = sum_{k in q-slice} ybar[k] * Wv[k][col]  (64 blocks) -------
__global__ __launch_bounds__(256) void k_head0(const float* __restrict__ y,
                                               const float* __restrict__ qkvw,
                                               float* __restrict__ zp) {
  __shared__ float yb[256];
  __shared__ float part[4][64];
  int blk = blockIdx.x;          // 64 = h*4 + q
  int h = blk >> 2, q = blk & 3;
  int t = threadIdx.x;
  int k0 = q * 256;
  {
    float s = 0.f;
    int k = k0 + t;
    #pragma unroll 8
    for (int p = 0; p < 64; p++) s += y[((size_t)(p * 16 + h) << 10) + k];
    yb[t] = s * (1.f / 32.f);
  }
  __syncthreads();
  int col = t & 63, g = t >> 6;   // 4 k-groups of 64
  float acc = 0.f;
  #pragma unroll 8
  for (int kk = 0; kk < 64; kk++) {
    int k = g * 64 + kk;
    acc = fmaf(yb[k], qkvw[(size_t)(k0 + k) * TC_ + 2048 + h * 64 + col], acc);
  }
  part[g][col] = acc;
  __syncthreads();
  if (t < 64)
    zp[(size_t)q * 1024 + h * 64 + t] = part[0][t] + part[1][t] + part[2][t] + part[3][t];
}

// ---------------- mu = 2*((Σq zp + bv) @ proj_w + proj_b)  [32 blocks x 32 cols] ----------------
__global__ __launch_bounds__(256) void k_head1(const float* __restrict__ zp,
                                               const float* __restrict__ qkvb,
                                               const float* __restrict__ pw,
                                               const float* __restrict__ pb,
                                               float* __restrict__ mu) {
  __shared__ float zs[1024];
  __shared__ float part[8][32];
  int t = threadIdx.x;
  for (int j = t; j < 1024; j += 256)
    zs[j] = zp[j] + zp[1024 + j] + zp[2048 + j] + zp[3072 + j] + qkvb[2048 + j];
  __syncthreads();
  int col = blockIdx.x * 32 + (t & 31), q = t >> 5;
  float acc = 0.f;
  #pragma unroll 4
  for (int k = q * 128; k < q * 128 + 128; k++)
    acc = fmaf(zs[k], pw[(size_t)k * 1024 + col], acc);
  part[q][t & 31] = acc;
  __syncthreads();
  if (t < 32) {
    float s = pb[blockIdx.x * 32 + t];
    #pragma unroll
    for (int p = 0; p < 8; p++) s += part[p][t];
    mu[blockIdx.x * 32 + t] = 2.f * s;
  }
}

// ---------------- eps (JAX threefry, partitionable) ----------------
__device__ __forceinline__ uint2 threefry_0_42(u32 x0, u32 x1) {
  const u32 ks0 = 0u, ks1 = 42u, ks2 = 0x1BD11BF0u;
  x0 += ks0; x1 += ks1;
  #define RND(r) { x0 += x1; x1 = (x1 << r) | (x1 >> (32 - r)); x1 ^= x0; }
  RND(13) RND(15) RND(26) RND(6)   x0 += ks1; x1 += ks2 + 1u;
  RND(17) RND(29) RND(16) RND(24)  x0 += ks2; x1 += ks0 + 2u;
  RND(13) RND(15) RND(26) RND(6)   x0 += ks0; x1 += ks1 + 3u;
  RND(17) RND(29) RND(16) RND(24)  x0 += ks1; x1 += ks2 + 4u;
  RND(13) RND(15) RND(26) RND(6)   x0 += ks2; x1 += ks0 + 5u;
  #undef RND
  return make_uint2(x0, x1);
}

__device__ __forceinline__ float bits_to_normal(u32 bits) {
  u32 fb = (bits >> 9) | 0x3F800000u;
  float fl = __builtin_bit_cast(float, fb) - 1.0f;
  float u = __fmul_rn(fl, 2.0f);
  u = __fadd_rn(u, -0.99999994f);
  u = fmaxf(-0.99999994f, u);
  float x = u;
  float wv = -log1pf(-x * x);
  float p;
  if (wv < 5.0f) {
    wv -= 2.5f;
    p = 2.81022636e-08f;
    p = fmaf(p, wv, 3.43273939e-07f);
    p = fmaf(p, wv, -3.5233877e-06f);
    p = fmaf(p, wv, -4.39150654e-06f);
    p = fmaf(p, wv, 0.00021858087f);
    p = fmaf(p, wv, -0.00125372503f);
    p = fmaf(p, wv, -0.00417768164f);
    p = fmaf(p, wv, 0.246640727f);
    p = fmaf(p, wv, 1.50140941f);
  } else {
    wv = sqrtf(wv) - 3.0f;
    p = -0.000200214257f;
    p = fmaf(p, wv, 0.000100950558f);
    p = fmaf(p, wv, 0.00134934322f);
    p = fmaf(p, wv, -0.00367342844f);
    p = fmaf(p, wv, 0.00573950773f);
    p = fmaf(p, wv, -0.0076224613f);
    p = fmaf(p, wv, 0.00943887047f);
    p = fmaf(p, wv, 1.00167406f);
    p = fmaf(p, wv, 2.83297682f);
  }
  return 1.41421356f * (p * x);
}

// ----- sigma = 0.1 + 0.9*sigmoid(mu@sig_w + sig_b), fused with latent write [32 blocks] -----
__global__ __launch_bounds__(256) void k_head2(const float* __restrict__ mu,
                                               const float* __restrict__ sw,
                                               const float* __restrict__ sb,
                                               float* __restrict__ out) {
  __shared__ float ms[1024];
  __shared__ float part[8][32];
  __shared__ float sigs[32];
  int t = threadIdx.x;
  for (int j = t; j < 1024; j += 256) ms[j] = mu[j];
  __syncthreads();
  int col = blockIdx.x * 32 + (t & 31), q = t >> 5;
  float acc = 0.f;
  #pragma unroll 4
  for (int k = q * 128; k < q * 128 + 128; k++)
    acc = fmaf(ms[k], sw[(size_t)k * 1024 + col], acc);
  part[q][t & 31] = acc;
  __syncthreads();
  if (t < 32) {
    float s = sb[blockIdx.x * 32 + t];
    #pragma unroll
    for (int p = 0; p < 8; p++) s += part[p][t];
    sigs[t] = 0.1f + 0.9f / (1.f + expf(-s));
  }
  __syncthreads();
  int c0 = blockIdx.x * 32;
  #pragma unroll
  for (int e = t; e < 64 * 32; e += 256) {
    int row = e >> 5, cc = e & 31;
    u32 f = (u32)row * 1024 + c0 + cc;
    uint2 rb = threefry_0_42(0u, f);
    float eps = bits_to_normal(rb.x ^ rb.y);
    out[f] = ms[c0 + cc] + sigs[cc] * eps;
  }
}

extern "C" void kernel_launch(void* const* d_in, const int* in_sizes, int n_in,
                              void* d_out, int out_size, void* d_ws, size_t ws_size,
                              hipStream_t stream) {
  const float* r    = (const float*)d_in[0];
  const float* lng  = (const float*)d_in[1];
  const float* lnb  = (const float*)d_in[2];
  const float* qkvw = (const float*)d_in[3];
  const float* qkvb = (const float*)d_in[4];
  const float* pw   = (const float*)d_in[5];
  const float* pb   = (const float*)d_in[6];
  const float* sw   = (const float*)d_in[7];
  const float* sb   = (const float*)d_in[8];
  float* out = (float*)d_out;

  u16* X   = (u16*)d_ws;                           // 32 MiB
  u16* QK  = X + (size_t)M_ * C_;                  // 64 MiB (2 planes: Q,K)
  u16* WT  = QK + (size_t)2 * M_ * C_;             // 4 MiB (bf16 [2048][1024])
  float* CW = (float*)(WT + (size_t)NQK_ * C_);    // 1 MiB (512*512 f32)
  float* Y2 = CW + (size_t)B_ * H_ * N_;           // 4 MiB (64*16*1024 f32)
  float* ZP = Y2 + (size_t)64 * H_ * C_;           // 16 KB (4*1024 partials)
  float* MU = ZP + 4 * C_;                         // 4 KB

  k_pre<<<M_ + NQK_, 256, 0, stream>>>(r, lng, lnb, qkvw, X, WT);
  k_qk<<<M_ / 128 * (NQK_ / 128), 256, 0, stream>>>(X, WT, qkvb, QK);
  k_attn<<<B_ * H_, 512, 0, stream>>>(QK, CW);
  k_ybar<<<512, 256, 0, stream>>>(CW, X, Y2);
  k_head0<<<64, 256, 0, stream>>>(Y2, qkvw, ZP);
  k_head1<<<32, 256, 0, stream>>>(ZP, qkvb, pw, pb, MU);
  k_head2<<<32, 256, 0, stream>>>(MU, sw, sb, out);
}